// Round 12
// baseline (2219.572 us; speedup 1.0000x reference)
//
#include <hip/hip_runtime.h>
#include <hip/hip_bf16.h>
#include <math.h>

#define DIMD 512
#define SEQL 4096
#define KU 1024
#define KF 1536
#define NJ 8192
#define KC 384          // OpenBLAS sgemm K-blocking (matched in round 5)
#define NTK 32          // KU/32 k-tiles

#define BM 64
#define BK 32
#define PA 33
#define PW 68

#define GAP_T 1e-3f

// ---- ws layout (bytes) ----
#define WS_R    0u          // 512 f32
#define WS_BC   4096u       // 2*8192 f32 (m-path combined bias, f64-folded)
#define WS_BCE  69632u      // 8192 f32 (e-path combined bias, f64-folded)
#define WS_CNT  102400u     // int counter
#define WS_WL   102656u     // worklist (2.1M ints max)
#define WS_UHI  8491264u    // 4096*1024 bf16, fragment order
#define WS_ULO  16879872u   // 4096*1024 bf16, fragment order
#define WS_WHI  25268480u   // 2*8192*1024 bf16 (Wnn,Wno hi), fragment order
#define WS_WLO  58822912u   // 2*8192*1024 bf16 (lo), fragment order
#define WS_WEH  92377344u   // 8192*1024 bf16 (W_E hi), fragment order
#define WS_NEEDED 109154560u

typedef __attribute__((ext_vector_type(8))) short bf16x8;
typedef __attribute__((ext_vector_type(4))) float f32x4;

__device__ __forceinline__ ushort f2bf(float f) {
    __hip_bfloat16 h = __float2bfloat16(f);
    return *reinterpret_cast<ushort*>(&h);
}
__device__ __forceinline__ float bf2f(ushort v) {
    unsigned int b = ((unsigned int)v) << 16;
    return __uint_as_float(b);
}

// async global->LDS, 16B per lane: dst is wave-uniform base, HW adds lane*16
__device__ __forceinline__ void gl16(const ushort* g, ushort* l) {
    __builtin_amdgcn_global_load_lds(
        (const __attribute__((address_space(1))) unsigned int*)g,
        (__attribute__((address_space(3))) unsigned int*)l,
        16, 0, 0);
}

// ---- f32 R with the exact chunked fma chain (k-ascending, KC blocks) ----
__device__ __forceinline__ float chainR(
    const float* __restrict__ h, const float* __restrict__ us, const float* __restrict__ ue,
    const float* __restrict__ Wr, const float* __restrict__ br, int o)
{
    float accT = 0.f;
    for (int k0 = 0; k0 < 2560; k0 += KC) {
        int ke = (k0 + KC < 2560) ? k0 + KC : 2560;
        float accC = 0.f;
        for (int k = k0; k < ke; ++k) {
            float xv = (k < 1536) ? h[k] : (k < 2048) ? us[k - 1536] : ue[k - 2048];
            accC = fmaf(xv, Wr[(size_t)o * 2560 + k], accC);
        }
        accT = __fadd_rn(accT, accC);
    }
    return __fadd_rn(accT, br[o]);
}

// ---- R: 8 blocks x 64 outputs; Wr staged to LDS coalesced; exact chain order ----
#define KCP 385
__global__ __launch_bounds__(256) void k_R32(
    const float* __restrict__ h, const float* __restrict__ us, const float* __restrict__ ue,
    const float* __restrict__ Wr, const float* __restrict__ br,
    float* __restrict__ Rout, int* __restrict__ cnt)
{
    __shared__ float xs[2560];
    __shared__ float Wsh[64 * KCP];
    if (blockIdx.x == 0 && threadIdx.x == 0) *cnt = 0;
    const int tid = threadIdx.x;
    const int o0 = blockIdx.x * 64;
    for (int k = tid; k < 2560; k += 256)
        xs[k] = (k < 1536) ? h[k] : (k < 2048) ? us[k - 1536] : ue[k - 2048];
    float accT = 0.f;
    for (int c = 0; c < 7; ++c) {
        int k0 = c * KC;
        int len = (k0 + KC <= 2560) ? KC : (2560 - k0);
        __syncthreads();
        for (int idx = tid * 4; idx < 64 * len; idx += 1024) {
            int r = idx / len, kk = idx - r * len;
            *(float4*)&Wsh[r * KCP + kk] = *(const float4*)&Wr[(size_t)(o0 + r) * 2560 + k0 + kk];
        }
        __syncthreads();
        if (tid < 64) {
            float accC = 0.f;
            for (int k = 0; k < len; ++k)
                accC = fmaf(xs[k0 + k], Wsh[tid * KCP + k], accC);
            accT = __fadd_rn(accT, accC);
        }
    }
    if (tid < 64) Rout[o0 + tid] = __fadd_rn(accT, br[o0 + tid]);
}

// ---- prep u: block per s16-tile; coalesced read -> LDS -> coalesced frag write ----
#define LPAD 1032
__global__ __launch_bounds__(256) void k_prep_u(
    const float* __restrict__ u, ushort* __restrict__ uhi, ushort* __restrict__ ulo)
{
    __shared__ ushort hs[16 * LPAD], ls[16 * LPAD];
    const int tid = threadIdx.x;
    const int t16 = blockIdx.x;
    #pragma unroll
    for (int it = 0; it < 16; ++it) {
        int k = tid * 4;
        float4 v = *(const float4*)&u[((size_t)t16 * 16 + it) * KU + k];
        ushort4 a, b;
        a.x = f2bf(v.x); b.x = f2bf(v.x - bf2f(a.x));
        a.y = f2bf(v.y); b.y = f2bf(v.y - bf2f(a.y));
        a.z = f2bf(v.z); b.z = f2bf(v.z - bf2f(a.z));
        a.w = f2bf(v.w); b.w = f2bf(v.w - bf2f(a.w));
        *(ushort4*)&hs[it * LPAD + k] = a;
        *(ushort4*)&ls[it * LPAD + k] = b;
    }
    __syncthreads();
    #pragma unroll
    for (int ct = 0; ct < 8; ++ct) {
        int c = ct * 256 + tid;
        int k32 = c >> 6, l = c & 63;
        int src = (l & 15) * LPAD + k32 * 32 + (l >> 4) * 8;
        size_t dst = (((size_t)t16 * NTK + k32) * 64 + l) * 8;
        *(uint4*)&uhi[dst] = *(const uint4*)&hs[src];
        *(uint4*)&ulo[dst] = *(const uint4*)&ls[src];
    }
}

// ---- prep Wnn/Wno: block per (mat, j16); hi+lo ----
__global__ __launch_bounds__(256) void k_prep_w(
    const float* __restrict__ Wnn, const float* __restrict__ Wno,
    ushort* __restrict__ whi, ushort* __restrict__ wlo)
{
    __shared__ ushort hs[16 * LPAD], ls[16 * LPAD];
    const int tid = threadIdx.x;
    const int mat = blockIdx.x >> 9, j16 = blockIdx.x & 511;
    const float* W = mat ? Wno : Wnn;
    #pragma unroll
    for (int it = 0; it < 16; ++it) {
        int k = tid * 4;
        float4 v = *(const float4*)&W[((size_t)j16 * 16 + it) * KF + k];
        ushort4 a, b;
        a.x = f2bf(v.x); b.x = f2bf(v.x - bf2f(a.x));
        a.y = f2bf(v.y); b.y = f2bf(v.y - bf2f(a.y));
        a.z = f2bf(v.z); b.z = f2bf(v.z - bf2f(a.z));
        a.w = f2bf(v.w); b.w = f2bf(v.w - bf2f(a.w));
        *(ushort4*)&hs[it * LPAD + k] = a;
        *(ushort4*)&ls[it * LPAD + k] = b;
    }
    __syncthreads();
    #pragma unroll
    for (int ct = 0; ct < 8; ++ct) {
        int c = ct * 256 + tid;
        int k32 = c >> 6, l = c & 63;
        int src = (l & 15) * LPAD + k32 * 32 + (l >> 4) * 8;
        size_t dst = ((((size_t)mat * 512 + j16) * NTK + k32) * 64 + l) * 8;
        *(uint4*)&whi[dst] = *(const uint4*)&hs[src];
        *(uint4*)&wlo[dst] = *(const uint4*)&ls[src];
    }
}

// ---- prep W_E: block per j16; hi only ----
__global__ __launch_bounds__(256) void k_prep_we(
    const float* __restrict__ WE, ushort* __restrict__ weh)
{
    __shared__ ushort hs[16 * LPAD];
    const int tid = threadIdx.x;
    const int j16 = blockIdx.x;
    #pragma unroll
    for (int it = 0; it < 16; ++it) {
        int k = tid * 4;
        float4 v = *(const float4*)&WE[((size_t)j16 * 16 + it) * KF + k];
        ushort4 a;
        a.x = f2bf(v.x); a.y = f2bf(v.y); a.z = f2bf(v.z); a.w = f2bf(v.w);
        *(ushort4*)&hs[it * LPAD + k] = a;
    }
    __syncthreads();
    #pragma unroll
    for (int ct = 0; ct < 8; ++ct) {
        int c = ct * 256 + tid;
        int k32 = c >> 6, l = c & 63;
        int src = (l & 15) * LPAD + k32 * 32 + (l >> 4) * 8;
        size_t dst = (((size_t)j16 * NTK + k32) * 64 + l) * 8;
        *(uint4*)&weh[dst] = *(const uint4*)&hs[src];
    }
}

// ---- merged bias: mat 0,1 -> Bc; mat 2 -> Bce (f64 fold, wave per output) ----
__global__ __launch_bounds__(256) void k_bias(
    const float* __restrict__ R32,
    const float* __restrict__ Wnn, const float* __restrict__ Wno, const float* __restrict__ WE,
    const float* __restrict__ bnn, const float* __restrict__ bno, const float* __restrict__ bE,
    float* __restrict__ Bc, float* __restrict__ Bce)
{
    int wid = blockIdx.x * 4 + (threadIdx.x >> 6);   // 0..24575
    int l = threadIdx.x & 63;
    int mat = wid >> 13, j = wid & 8191;
    const float* W = (mat == 0) ? Wnn : (mat == 1) ? Wno : WE;
    const float* b = (mat == 0) ? bnn : (mat == 1) ? bno : bE;
    double acc = 0.0;
    for (int k = 1024 + l; k < 1536; k += 64)
        acc += (double)R32[k - KU] * (double)W[(size_t)j * KF + k];
    for (int off = 32; off > 0; off >>= 1) acc += __shfl_down(acc, off);
    if (l == 0) {
        float r = (float)(acc + (double)b[j]);
        if (mat < 2) Bc[wid] = r; else Bce[j] = r;
    }
}

// ---- fused m+e kernel: gload_lds staging, XCD swizzle, shuffle gate ----
struct MSt {
    ushort u1[4096], u2[4096];    // 8 s16-tiles x 64 lanes x 8
    ushort w1[4096], w2[4096];    // (2 mats x 4 j16-tiles) x 64 x 8
    ushort we[2048];              // 4 j16-tiles x 64 x 8
};                                // 36864 B

__global__ __launch_bounds__(256, 3) void k_m(
    const ushort* __restrict__ uhi, const ushort* __restrict__ ulo,
    const ushort* __restrict__ whi, const ushort* __restrict__ wlo,
    const ushort* __restrict__ weh,
    const float* __restrict__ noise,
    const float* __restrict__ Bc, const float* __restrict__ Bce,
    int* __restrict__ cnt, int* __restrict__ wl, float* __restrict__ out)
{
    __shared__ MSt sm;
    const int tid = threadIdx.x;
    const int w = tid >> 6, l = tid & 63;
    const int wm = w >> 1, wn = w & 1;
    const int lr = l & 15, lq = l >> 4;
    const int l8 = l * 8;
    // XCD swizzle: each XCD walks one 64-col W panel across all 32 s-tiles
    const int b = blockIdx.y * 128 + blockIdx.x;     // 4096 blocks, %8==0
    const int xcd = b & 7, t5 = b >> 3;
    const int jB16 = (xcd * 16 + (t5 >> 5)) * 4;
    const int sB16 = (t5 & 31) * 8;
    const int jBase = jB16 * 16;
    const int sBase = sB16 * 16;
    const int dBase = jBase >> 4;

    f32x4 acc1[4][2] = {}, acc2[4][2] = {}, accE[4][2] = {};

    for (int kt = 0; kt < NTK; ++kt) {
        __syncthreads();
        // 36 wave-group loads (9 per wave), direct global->LDS
        #pragma unroll
        for (int i = 0; i < 9; ++i) {
            int g = w * 9 + i;
            const ushort* src;
            ushort* dst;
            if (g < 16) {
                int t = g & 7;
                size_t off = (((size_t)(sB16 + t) * NTK + kt) * 64 + l) * 8;
                src = ((g < 8) ? uhi : ulo) + off;
                dst = ((g < 8) ? sm.u1 : sm.u2) + t * 512;
            } else if (g < 32) {
                int ii = g & 7;
                size_t off = ((((size_t)(ii >> 2) * 512 + jB16 + (ii & 3)) * NTK + kt) * 64 + l) * 8;
                src = ((g < 24) ? whi : wlo) + off;
                dst = ((g < 24) ? sm.w1 : sm.w2) + ii * 512;
            } else {
                int jt = g - 32;
                size_t off = (((size_t)(jB16 + jt) * NTK + kt) * 64 + l) * 8;
                src = weh + off;
                dst = sm.we + jt * 512;
            }
            gl16(src, dst);
        }
        __syncthreads();
        bf16x8 a1[4], a2[4];
        #pragma unroll
        for (int i = 0; i < 4; ++i) {
            int base = (wm * 4 + i) * 512 + l8;
            a1[i] = *(const bf16x8*)&sm.u1[base];
            a2[i] = *(const bf16x8*)&sm.u2[base];
        }
        #pragma unroll
        for (int n = 0; n < 2; ++n) {
            int jloc = wn * 2 + n;
            {   // mat 0 -> acc1
                bf16x8 p1 = *(const bf16x8*)&sm.w1[jloc * 512 + l8];
                bf16x8 p2 = *(const bf16x8*)&sm.w2[jloc * 512 + l8];
                #pragma unroll
                for (int i = 0; i < 4; ++i) {
                    acc1[i][n] = __builtin_amdgcn_mfma_f32_16x16x32_bf16(a1[i], p1, acc1[i][n], 0, 0, 0);
                    acc1[i][n] = __builtin_amdgcn_mfma_f32_16x16x32_bf16(a1[i], p2, acc1[i][n], 0, 0, 0);
                    acc1[i][n] = __builtin_amdgcn_mfma_f32_16x16x32_bf16(a2[i], p1, acc1[i][n], 0, 0, 0);
                }
            }
            {   // mat 1 -> acc2
                bf16x8 p1 = *(const bf16x8*)&sm.w1[(4 + jloc) * 512 + l8];
                bf16x8 p2 = *(const bf16x8*)&sm.w2[(4 + jloc) * 512 + l8];
                #pragma unroll
                for (int i = 0; i < 4; ++i) {
                    acc2[i][n] = __builtin_amdgcn_mfma_f32_16x16x32_bf16(a1[i], p1, acc2[i][n], 0, 0, 0);
                    acc2[i][n] = __builtin_amdgcn_mfma_f32_16x16x32_bf16(a1[i], p2, acc2[i][n], 0, 0, 0);
                    acc2[i][n] = __builtin_amdgcn_mfma_f32_16x16x32_bf16(a2[i], p1, acc2[i][n], 0, 0, 0);
                }
            }
            {   // E -> accE
                bf16x8 pe = *(const bf16x8*)&sm.we[jloc * 512 + l8];
                #pragma unroll
                for (int i = 0; i < 4; ++i)
                    accE[i][n] = __builtin_amdgcn_mfma_f32_16x16x32_bf16(a1[i], pe, accE[i][n], 0, 0, 0);
            }
        }
    }

    // ---- epilogue: in-register gate via lr-group butterflies ----
    float bc1[2], bc2[2], be[2];
    #pragma unroll
    for (int n = 0; n < 2; ++n) {
        int col = jBase + wn * 32 + n * 16 + lr;
        bc1[n] = Bc[col];
        bc2[n] = Bc[NJ + col];
        be[n]  = Bce[col];
    }
    const int gbase = l & 48;       // lr-group base lane
    #pragma unroll
    for (int i = 0; i < 4; ++i)
        #pragma unroll
        for (int n = 0; n < 2; ++n) {
            int colL = wn * 32 + n * 16 + lr;
            int dloc = wn * 2 + n;
            #pragma unroll
            for (int r = 0; r < 4; ++r) {
                int rowL = wm * 64 + i * 16 + lq * 4 + r;
                float m1 = acc1[i][n][r] + bc1[n];
                float m2 = acc2[i][n][r] + bc2[n];
                float nz = noise[(size_t)(sBase + rowL) * NJ + jBase + colL];
                float m  = fmaf(m2, nz, m1);
                float ev = accE[i][n][r] + be[n];
                float v1 = m; int i1 = lr;
                #pragma unroll
                for (int mk = 1; mk <= 8; mk <<= 1) {
                    float ov = __shfl_xor(v1, mk);
                    int oi = __shfl_xor(i1, mk);
                    if (ov > v1 || (ov == v1 && oi < i1)) { v1 = ov; i1 = oi; }
                }
                float v2 = (lr == i1) ? -INFINITY : m;
                int i2 = (lr == i1) ? 64 : lr;
                #pragma unroll
                for (int mk = 1; mk <= 8; mk <<= 1) {
                    float ov = __shfl_xor(v2, mk);
                    int oi = __shfl_xor(i2, mk);
                    if (ov > v2 || (ov == v2 && oi < i2)) { v2 = ov; i2 = oi; }
                }
                float v3 = (lr == i1 || lr == i2) ? -INFINITY : m;
                #pragma unroll
                for (int mk = 1; mk <= 8; mk <<= 1)
                    v3 = fmaxf(v3, __shfl_xor(v3, mk));
                float ev1 = __shfl(ev, gbase + i1);
                float ev2 = __shfl(ev, gbase + (i2 & 15));
                if (lr == 0) {
                    int gidx = (sBase + rowL) * DIMD + dBase + dloc;
                    bool flg = (v2 - v3 < GAP_T) || (fabsf(v1) < GAP_T) || (fabsf(v2) < GAP_T);
                    if (flg) {
                        int pos = atomicAdd(cnt, 1);
                        wl[pos] = gidx;
                    }
                    double x1 = (double)v1, x2 = (double)v2;
                    double vmax = fmax(x1, x2);
                    double g1 = exp(x1 - vmax), g2 = exp(x2 - vmax);
                    double num = g1 * (double)ev1 + g2 * (double)ev2;
                    out[gidx] = (float)(num / (g1 + g2) * 0.0625);
                }
            }
        }
}

// ---- repair: one wave per flagged site; lane = (expert, mat) exact chain ----
__global__ __launch_bounds__(256) void k_repair(
    const float* __restrict__ u, const float* __restrict__ noise,
    const float* __restrict__ Wnn, const float* __restrict__ Wno, const float* __restrict__ WE,
    const float* __restrict__ bnn, const float* __restrict__ bno, const float* __restrict__ bE,
    const float* __restrict__ R32,
    const int* __restrict__ cnt, const int* __restrict__ wl, float* __restrict__ out)
{
    const int l = threadIdx.x & 63;
    const int e = l & 15, mt = l >> 4;          // mt in 0..3 (3 idle)
    const int wid = (blockIdx.x * 256 + threadIdx.x) >> 6;
    const int NW = (512 * 256) >> 6;
    const int n = *cnt;

    for (int i = wid; i < n; i += NW) {
        int si = wl[i];
        int s = si >> 9, d = si & 511;
        int j = d * 16 + e;
        const float* urow = u + (size_t)s * KU;
        float t = 0.f;
        if (mt < 3) {
            const float* Wrow = (mt == 0 ? Wnn : (mt == 1 ? Wno : WE)) + (size_t)j * KF;
            #pragma unroll
            for (int c = 0; c < 4; ++c) {
                float cc = 0.f;
                int k0 = c * KC;
                for (int k = k0; k < k0 + KC; ++k) {
                    float a = (k < KU) ? urow[k] : R32[k - KU];
                    cc = fmaf(a, Wrow[k], cc);
                }
                t = __fadd_rn(t, cc);
            }
            t = __fadd_rn(t, (mt == 0 ? bnn : (mt == 1 ? bno : bE))[j]);
        }
        float h2 = __shfl(t, 16 + e);
        float ee = __shfl(t, 32 + e);
        float m = -INFINITY;
        if (mt == 0)
            m = __fadd_rn(t, __fmul_rn(h2, noise[(size_t)s * NJ + j]));
        float v1 = m; int i1 = e;
        #pragma unroll
        for (int mk = 1; mk <= 8; mk <<= 1) {
            float ov = __shfl_xor(v1, mk);
            int oi = __shfl_xor(i1, mk);
            if (ov > v1 || (ov == v1 && oi < i1)) { v1 = ov; i1 = oi; }
        }
        float v2 = (mt == 0 && e == i1) ? -INFINITY : m;
        int i2 = (mt == 0 && e == i1) ? 64 : e;
        #pragma unroll
        for (int mk = 1; mk <= 8; mk <<= 1) {
            float ov = __shfl_xor(v2, mk);
            int oi = __shfl_xor(i2, mk);
            if (ov > v2 || (ov == v2 && oi < i2)) { v2 = ov; i2 = oi; }
        }
        float se = ee;
        #pragma unroll
        for (int mk = 1; mk <= 8; mk <<= 1) se += __shfl_xor(se, mk);
        float ev1 = __shfl(ee, i1);
        float ev2 = __shfl(ee, i2 & 15);
        if (l == 0) {
            double x1 = (v1 == 0.0f) ? -100000.0 : (double)v1;
            double x2 = (v2 == 0.0f) ? -100000.0 : (double)v2;
            double vmax = fmax(fmax(x1, x2), -100000.0);
            double g1 = exp(x1 - vmax), g2 = exp(x2 - vmax), gz = exp(-100000.0 - vmax);
            double den = g1 + g2 + 14.0 * gz;
            double num = g1 * (double)ev1 + g2 * (double)ev2
                       + gz * ((double)se - (double)ev1 - (double)ev2);
            out[si] = (float)(num / den * 0.0625);
        }
    }
}

// ---- fallback: proven round-5 ws-free kernel (bit-identical arithmetic) ----
__global__ __launch_bounds__(256) void k_base(
    const float* __restrict__ u, const float* __restrict__ noise,
    const float* __restrict__ Wnn, const float* __restrict__ Wno, const float* __restrict__ WE,
    const float* __restrict__ bnn, const float* __restrict__ bno, const float* __restrict__ bE,
    const float* __restrict__ h, const float* __restrict__ us, const float* __restrict__ ue,
    const float* __restrict__ Wr, const float* __restrict__ br,
    float* __restrict__ out)
{
    __shared__ __align__(16) float As[BM][PA];
    __shared__ __align__(16) float Ws[3][BK][PW];
    __shared__ float Rsh[512];

    const int tid = threadIdx.x;
    const int sr = tid >> 2, dl = tid & 3;
    const int jBase = blockIdx.x * 64;
    const int sBase = blockIdx.y * BM;
    const int myCol = dl * 16;

    for (int o = tid; o < 512; o += 256) Rsh[o] = chainR(h, us, ue, Wr, br, o);

    float t1[16] = {}, c1[16] = {}, t2[16] = {}, c2[16] = {}, tE[16] = {}, cE[16] = {};

    for (int kt = 0; kt < KF; kt += BK) {
        __syncthreads();
        if (kt < KU) {
            for (int idx = tid; idx < BM * BK; idx += 256) {
                int r = idx >> 5, c = idx & 31;
                As[r][c] = u[(size_t)(sBase + r) * KU + kt + c];
            }
        }
        for (int idx = tid; idx < 64 * BK; idx += 256) {
            int col = idx >> 5, kk = idx & 31;
            size_t off = (size_t)(jBase + col) * KF + kt + kk;
            Ws[0][kk][col] = Wnn[off];
            Ws[1][kk][col] = Wno[off];
            Ws[2][kk][col] = WE[off];
        }
        __syncthreads();
        const bool uReg = (kt < KU);
        for (int kk = 0; kk < BK; ++kk) {
            float a = uReg ? As[sr][kk] : Rsh[kt + kk - KU];
            #pragma unroll
            for (int q = 0; q < 4; ++q) {
                float4 w0 = *(const float4*)&Ws[0][kk][myCol + 4 * q];
                float4 w1 = *(const float4*)&Ws[1][kk][myCol + 4 * q];
                float4 w2 = *(const float4*)&Ws[2][kk][myCol + 4 * q];
                c1[4*q+0] = fmaf(a, w0.x, c1[4*q+0]);
                c1[4*q+1] = fmaf(a, w0.y, c1[4*q+1]);
                c1[4*q+2] = fmaf(a, w0.z, c1[4*q+2]);
                c1[4*q+3] = fmaf(a, w0.w, c1[4*q+3]);
                c2[4*q+0] = fmaf(a, w1.x, c2[4*q+0]);
                c2[4*q+1] = fmaf(a, w1.y, c2[4*q+1]);
                c2[4*q+2] = fmaf(a, w1.z, c2[4*q+2]);
                c2[4*q+3] = fmaf(a, w1.w, c2[4*q+3]);
                cE[4*q+0] = fmaf(a, w2.x, cE[4*q+0]);
                cE[4*q+1] = fmaf(a, w2.y, cE[4*q+1]);
                cE[4*q+2] = fmaf(a, w2.z, cE[4*q+2]);
                cE[4*q+3] = fmaf(a, w2.w, cE[4*q+3]);
            }
        }
        if (((kt + BK) % KC) == 0 || (kt + BK) == KF) {
            #pragma unroll
            for (int e = 0; e < 16; ++e) {
                t1[e] = __fadd_rn(t1[e], c1[e]); c1[e] = 0.f;
                t2[e] = __fadd_rn(t2[e], c2[e]); c2[e] = 0.f;
                tE[e] = __fadd_rn(tE[e], cE[e]); cE[e] = 0.f;
            }
        }
    }

    const int s = sBase + sr;
    const int jb = jBase + myCol;
    float m32[16]; double evv[16];
    #pragma unroll
    for (int e = 0; e < 16; ++e) {
        float h1 = __fadd_rn(t1[e], bnn[jb + e]);
        float h2 = __fadd_rn(t2[e], bno[jb + e]);
        float nz = noise[(size_t)s * NJ + jb + e];
        m32[e] = __fadd_rn(h1, __fmul_rn(h2, nz));
        evv[e] = (double)__fadd_rn(tE[e], bE[jb + e]);
    }
    int i1 = 0; float v1 = m32[0];
    #pragma unroll
    for (int e = 1; e < 16; ++e) if (m32[e] > v1) { v1 = m32[e]; i1 = e; }
    int i2 = -1; float v2 = -INFINITY;
    #pragma unroll
    for (int e = 0; e < 16; ++e) if (e != i1 && m32[e] > v2) { v2 = m32[e]; i2 = e; }
    double e1 = 0.0, e2 = 0.0, sumE = 0.0;
    #pragma unroll
    for (int e = 0; e < 16; ++e) {
        e1 = (e == i1) ? evv[e] : e1;
        e2 = (e == i2) ? evv[e] : e2;
        sumE += evv[e];
    }
    double x1 = (v1 == 0.0f) ? -100000.0 : (double)v1;
    double x2 = (v2 == 0.0f) ? -100000.0 : (double)v2;
    double vmax = fmax(fmax(x1, x2), -100000.0);
    double g1 = exp(x1 - vmax), g2 = exp(x2 - vmax), gz = exp(-100000.0 - vmax);
    double den = g1 + g2 + 14.0 * gz;
    double num = g1 * e1 + g2 * e2 + gz * (sumE - e1 - e2);
    out[(size_t)s * DIMD + (jBase >> 4) + dl] = (float)(num / den * 0.0625);
}

extern "C" void kernel_launch(void* const* d_in, const int* in_sizes, int n_in,
                              void* d_out, int out_size, void* d_ws, size_t ws_size,
                              hipStream_t stream) {
    (void)in_sizes; (void)n_in; (void)out_size;
    const float* h     = (const float*)d_in[0];
    const float* us    = (const float*)d_in[1];
    const float* ue    = (const float*)d_in[2];
    const float* u     = (const float*)d_in[3];
    const float* noise = (const float*)d_in[4];
    const float* Wnn   = (const float*)d_in[5];
    const float* bnn   = (const float*)d_in[6];
    const float* Wno   = (const float*)d_in[7];
    const float* bno   = (const float*)d_in[8];
    const float* WE    = (const float*)d_in[9];
    const float* bE    = (const float*)d_in[10];
    const float* Wr    = (const float*)d_in[11];
    const float* br    = (const float*)d_in[12];
    float* out = (float*)d_out;

    if (ws_size >= WS_NEEDED) {
        char* ws = (char*)d_ws;
        float* Rws  = (float*)(ws + WS_R);
        float* Bc   = (float*)(ws + WS_BC);
        float* Bce  = (float*)(ws + WS_BCE);
        int*   cnt  = (int*)(ws + WS_CNT);
        int*   wl   = (int*)(ws + WS_WL);
        ushort* uhi = (ushort*)(ws + WS_UHI);
        ushort* ulo = (ushort*)(ws + WS_ULO);
        ushort* whi = (ushort*)(ws + WS_WHI);
        ushort* wlo = (ushort*)(ws + WS_WLO);
        ushort* weh = (ushort*)(ws + WS_WEH);

        hipLaunchKernelGGL(k_R32, dim3(8), dim3(256), 0, stream, h, us, ue, Wr, br, Rws, cnt);
        hipLaunchKernelGGL(k_prep_u, dim3(SEQL / 16), dim3(256), 0, stream, u, uhi, ulo);
        hipLaunchKernelGGL(k_prep_w, dim3(2 * NJ / 16), dim3(256), 0, stream, Wnn, Wno, whi, wlo);
        hipLaunchKernelGGL(k_prep_we, dim3(NJ / 16), dim3(256), 0, stream, WE, weh);
        hipLaunchKernelGGL(k_bias, dim3(6144), dim3(256), 0, stream,
                           Rws, Wnn, Wno, WE, bnn, bno, bE, Bc, Bce);
        hipLaunchKernelGGL(k_m, dim3(128, 32), dim3(256), 0, stream,
                           uhi, ulo, whi, wlo, weh, noise, Bc, Bce, cnt, wl, out);
        hipLaunchKernelGGL(k_repair, dim3(512), dim3(256), 0, stream,
                           u, noise, Wnn, Wno, WE, bnn, bno, bE, Rws, cnt, wl, out);
    } else {
        hipLaunchKernelGGL(k_base, dim3(NJ / 64, SEQL / BM), dim3(256), 0, stream,
                           u, noise, Wnn, Wno, WE, bnn, bno, bE,
                           h, us, ue, Wr, br, out);
    }
}

// Round 13
// 1629.450 us; speedup vs baseline: 1.3622x; 1.3622x over previous
//
#include <hip/hip_runtime.h>
#include <hip/hip_bf16.h>
#include <math.h>

#define DIMD 512
#define SEQL 4096
#define KU 1024
#define KF 1536
#define NJ 8192
#define KC 384          // OpenBLAS sgemm K-blocking (matched in round 5)
#define NTK 32          // KU/32 k-tiles

#define BM 64
#define BK 32
#define PA 33
#define PW 68

#define GAP_T 1e-3f

// ---- ws layout (bytes) ----
#define WS_R    0u          // 512 f32
#define WS_BC   4096u       // 2*8192 f32 (m-path combined bias, f64-folded)
#define WS_BCE  69632u      // 8192 f32 (e-path combined bias, f64-folded)
#define WS_CNT  102400u     // int counter
#define WS_WL   102656u     // worklist (2.1M ints max)
#define WS_UHI  8491264u    // 4096*1024 bf16, fragment order
#define WS_ULO  16879872u   // 4096*1024 bf16, fragment order
#define WS_WHI  25268480u   // 2*8192*1024 bf16 (Wnn,Wno hi), fragment order
#define WS_WLO  58822912u   // 2*8192*1024 bf16 (lo), fragment order
#define WS_WEH  92377344u   // 8192*1024 bf16 (W_E hi), fragment order
#define WS_NEEDED 109154560u

typedef __attribute__((ext_vector_type(8))) short bf16x8;
typedef __attribute__((ext_vector_type(4))) float f32x4;

__device__ __forceinline__ ushort f2bf(float f) {
    __hip_bfloat16 h = __float2bfloat16(f);
    return *reinterpret_cast<ushort*>(&h);
}
__device__ __forceinline__ float bf2f(ushort v) {
    unsigned int b = ((unsigned int)v) << 16;
    return __uint_as_float(b);
}

// ---- f32 R with the exact chunked fma chain (k-ascending, KC blocks) ----
__device__ __forceinline__ float chainR(
    const float* __restrict__ h, const float* __restrict__ us, const float* __restrict__ ue,
    const float* __restrict__ Wr, const float* __restrict__ br, int o)
{
    float accT = 0.f;
    for (int k0 = 0; k0 < 2560; k0 += KC) {
        int ke = (k0 + KC < 2560) ? k0 + KC : 2560;
        float accC = 0.f;
        for (int k = k0; k < ke; ++k) {
            float xv = (k < 1536) ? h[k] : (k < 2048) ? us[k - 1536] : ue[k - 2048];
            accC = fmaf(xv, Wr[(size_t)o * 2560 + k], accC);
        }
        accT = __fadd_rn(accT, accC);
    }
    return __fadd_rn(accT, br[o]);
}

// ---- R: 8 blocks x 64 outputs; Wr staged to LDS coalesced; exact chain order ----
#define KCP 385
__global__ __launch_bounds__(256) void k_R32(
    const float* __restrict__ h, const float* __restrict__ us, const float* __restrict__ ue,
    const float* __restrict__ Wr, const float* __restrict__ br,
    float* __restrict__ Rout, int* __restrict__ cnt)
{
    __shared__ float xs[2560];
    __shared__ float Wsh[64 * KCP];
    if (blockIdx.x == 0 && threadIdx.x == 0) *cnt = 0;
    const int tid = threadIdx.x;
    const int o0 = blockIdx.x * 64;
    for (int k = tid; k < 2560; k += 256)
        xs[k] = (k < 1536) ? h[k] : (k < 2048) ? us[k - 1536] : ue[k - 2048];
    float accT = 0.f;
    for (int c = 0; c < 7; ++c) {
        int k0 = c * KC;
        int len = (k0 + KC <= 2560) ? KC : (2560 - k0);
        __syncthreads();
        for (int idx = tid * 4; idx < 64 * len; idx += 1024) {
            int r = idx / len, kk = idx - r * len;
            *(float4*)&Wsh[r * KCP + kk] = *(const float4*)&Wr[(size_t)(o0 + r) * 2560 + k0 + kk];
        }
        __syncthreads();
        if (tid < 64) {
            float accC = 0.f;
            for (int k = 0; k < len; ++k)
                accC = fmaf(xs[k0 + k], Wsh[tid * KCP + k], accC);
            accT = __fadd_rn(accT, accC);
        }
    }
    if (tid < 64) Rout[o0 + tid] = __fadd_rn(accT, br[o0 + tid]);
}

// ---- prep u: block per s16-tile; coalesced read -> LDS -> coalesced frag write ----
#define LPAD 1032
__global__ __launch_bounds__(256) void k_prep_u(
    const float* __restrict__ u, ushort* __restrict__ uhi, ushort* __restrict__ ulo)
{
    __shared__ ushort hs[16 * LPAD], ls[16 * LPAD];
    const int tid = threadIdx.x;
    const int t16 = blockIdx.x;
    #pragma unroll
    for (int it = 0; it < 16; ++it) {
        int k = tid * 4;
        float4 v = *(const float4*)&u[((size_t)t16 * 16 + it) * KU + k];
        ushort4 a, b;
        a.x = f2bf(v.x); b.x = f2bf(v.x - bf2f(a.x));
        a.y = f2bf(v.y); b.y = f2bf(v.y - bf2f(a.y));
        a.z = f2bf(v.z); b.z = f2bf(v.z - bf2f(a.z));
        a.w = f2bf(v.w); b.w = f2bf(v.w - bf2f(a.w));
        *(ushort4*)&hs[it * LPAD + k] = a;
        *(ushort4*)&ls[it * LPAD + k] = b;
    }
    __syncthreads();
    #pragma unroll
    for (int ct = 0; ct < 8; ++ct) {
        int c = ct * 256 + tid;
        int k32 = c >> 6, l = c & 63;
        int src = (l & 15) * LPAD + k32 * 32 + (l >> 4) * 8;
        size_t dst = (((size_t)t16 * NTK + k32) * 64 + l) * 8;
        *(uint4*)&uhi[dst] = *(const uint4*)&hs[src];
        *(uint4*)&ulo[dst] = *(const uint4*)&ls[src];
    }
}

// ---- prep Wnn/Wno: block per (mat, j16); hi+lo ----
__global__ __launch_bounds__(256) void k_prep_w(
    const float* __restrict__ Wnn, const float* __restrict__ Wno,
    ushort* __restrict__ whi, ushort* __restrict__ wlo)
{
    __shared__ ushort hs[16 * LPAD], ls[16 * LPAD];
    const int tid = threadIdx.x;
    const int mat = blockIdx.x >> 9, j16 = blockIdx.x & 511;
    const float* W = mat ? Wno : Wnn;
    #pragma unroll
    for (int it = 0; it < 16; ++it) {
        int k = tid * 4;
        float4 v = *(const float4*)&W[((size_t)j16 * 16 + it) * KF + k];
        ushort4 a, b;
        a.x = f2bf(v.x); b.x = f2bf(v.x - bf2f(a.x));
        a.y = f2bf(v.y); b.y = f2bf(v.y - bf2f(a.y));
        a.z = f2bf(v.z); b.z = f2bf(v.z - bf2f(a.z));
        a.w = f2bf(v.w); b.w = f2bf(v.w - bf2f(a.w));
        *(ushort4*)&hs[it * LPAD + k] = a;
        *(ushort4*)&ls[it * LPAD + k] = b;
    }
    __syncthreads();
    #pragma unroll
    for (int ct = 0; ct < 8; ++ct) {
        int c = ct * 256 + tid;
        int k32 = c >> 6, l = c & 63;
        int src = (l & 15) * LPAD + k32 * 32 + (l >> 4) * 8;
        size_t dst = ((((size_t)mat * 512 + j16) * NTK + k32) * 64 + l) * 8;
        *(uint4*)&whi[dst] = *(const uint4*)&hs[src];
        *(uint4*)&wlo[dst] = *(const uint4*)&ls[src];
    }
}

// ---- prep W_E: block per j16; hi only ----
__global__ __launch_bounds__(256) void k_prep_we(
    const float* __restrict__ WE, ushort* __restrict__ weh)
{
    __shared__ ushort hs[16 * LPAD];
    const int tid = threadIdx.x;
    const int j16 = blockIdx.x;
    #pragma unroll
    for (int it = 0; it < 16; ++it) {
        int k = tid * 4;
        float4 v = *(const float4*)&WE[((size_t)j16 * 16 + it) * KF + k];
        ushort4 a;
        a.x = f2bf(v.x); a.y = f2bf(v.y); a.z = f2bf(v.z); a.w = f2bf(v.w);
        *(ushort4*)&hs[it * LPAD + k] = a;
    }
    __syncthreads();
    #pragma unroll
    for (int ct = 0; ct < 8; ++ct) {
        int c = ct * 256 + tid;
        int k32 = c >> 6, l = c & 63;
        int src = (l & 15) * LPAD + k32 * 32 + (l >> 4) * 8;
        size_t dst = (((size_t)j16 * NTK + k32) * 64 + l) * 8;
        *(uint4*)&weh[dst] = *(const uint4*)&hs[src];
    }
}

// ---- merged bias: mat 0,1 -> Bc; mat 2 -> Bce (f64 fold, wave per output) ----
__global__ __launch_bounds__(256) void k_bias(
    const float* __restrict__ R32,
    const float* __restrict__ Wnn, const float* __restrict__ Wno, const float* __restrict__ WE,
    const float* __restrict__ bnn, const float* __restrict__ bno, const float* __restrict__ bE,
    float* __restrict__ Bc, float* __restrict__ Bce)
{
    int wid = blockIdx.x * 4 + (threadIdx.x >> 6);   // 0..24575
    int l = threadIdx.x & 63;
    int mat = wid >> 13, j = wid & 8191;
    const float* W = (mat == 0) ? Wnn : (mat == 1) ? Wno : WE;
    const float* b = (mat == 0) ? bnn : (mat == 1) ? bno : bE;
    double acc = 0.0;
    for (int k = 1024 + l; k < 1536; k += 64)
        acc += (double)R32[k - KU] * (double)W[(size_t)j * KF + k];
    for (int off = 32; off > 0; off >>= 1) acc += __shfl_down(acc, off);
    if (l == 0) {
        float r = (float)(acc + (double)b[j]);
        if (mat < 2) Bc[wid] = r; else Bce[j] = r;
    }
}

// ---- fused m+e kernel: linear fragment LDS, shuffle gate (round-11 proven) ----
struct MSt {
    ushort u1[4096], u2[4096];    // 8 s16-tiles x 64 lanes x 8
    ushort w1[4096], w2[4096];    // (2 mats x 4 j16-tiles) x 64 x 8
    ushort we[2048];              // 4 j16-tiles x 64 x 8
};                                // 36864 B

__global__ __launch_bounds__(256, 3) void k_m(
    const ushort* __restrict__ uhi, const ushort* __restrict__ ulo,
    const ushort* __restrict__ whi, const ushort* __restrict__ wlo,
    const ushort* __restrict__ weh,
    const float* __restrict__ noise,
    const float* __restrict__ Bc, const float* __restrict__ Bce,
    int* __restrict__ cnt, int* __restrict__ wl, float* __restrict__ out)
{
    __shared__ MSt sm;
    const int tid = threadIdx.x;
    const int w = tid >> 6, l = tid & 63;
    const int wm = w >> 1, wn = w & 1;
    const int lr = l & 15, lq = l >> 4;
    const int l8 = l * 8;
    const int sBase = blockIdx.y * 128;
    const int sB16 = blockIdx.y * 8;
    const int jBase = blockIdx.x * 64;
    const int jB16 = blockIdx.x * 4;
    const int dBase = jBase >> 4;

    f32x4 acc1[4][2] = {}, acc2[4][2] = {}, accE[4][2] = {};

    for (int kt = 0; kt < NTK; ++kt) {
        __syncthreads();
        #pragma unroll
        for (int it = 0; it < 4; ++it) {            // u: 1024 x 16B
            int c = tid + it * 256;
            int buf = c >> 9, rem = c & 511;
            size_t g = (((size_t)(sB16 + (rem >> 6)) * NTK + kt) * 64 + (rem & 63)) * 8;
            const ushort* src = buf ? ulo : uhi;
            ushort* dst = (buf ? sm.u2 : sm.u1) + rem * 8;
            *(uint4*)dst = *(const uint4*)&src[g];
        }
        #pragma unroll
        for (int it = 0; it < 4; ++it) {            // w: 1024 x 16B
            int c = tid + it * 256;
            int buf = c >> 9, rem = c & 511;
            int mt = rem >> 8, jt = (rem >> 6) & 3;
            size_t g = ((((size_t)mt * 512 + jB16 + jt) * NTK + kt) * 64 + (rem & 63)) * 8;
            const ushort* src = buf ? wlo : whi;
            ushort* dst = (buf ? sm.w2 : sm.w1) + rem * 8;
            *(uint4*)dst = *(const uint4*)&src[g];
        }
        {                                           // we: 256 x 16B
            int jt = tid >> 6;
            size_t g = (((size_t)(jB16 + jt) * NTK + kt) * 64 + (tid & 63)) * 8;
            *(uint4*)&sm.we[tid * 8] = *(const uint4*)&weh[g];
        }
        __syncthreads();
        bf16x8 a1[4], a2[4];
        #pragma unroll
        for (int i = 0; i < 4; ++i) {
            int base = (wm * 4 + i) * 512 + l8;
            a1[i] = *(const bf16x8*)&sm.u1[base];
            a2[i] = *(const bf16x8*)&sm.u2[base];
        }
        #pragma unroll
        for (int n = 0; n < 2; ++n) {
            int jloc = wn * 2 + n;
            {   // mat 0 -> acc1
                bf16x8 p1 = *(const bf16x8*)&sm.w1[jloc * 512 + l8];
                bf16x8 p2 = *(const bf16x8*)&sm.w2[jloc * 512 + l8];
                #pragma unroll
                for (int i = 0; i < 4; ++i) {
                    acc1[i][n] = __builtin_amdgcn_mfma_f32_16x16x32_bf16(a1[i], p1, acc1[i][n], 0, 0, 0);
                    acc1[i][n] = __builtin_amdgcn_mfma_f32_16x16x32_bf16(a1[i], p2, acc1[i][n], 0, 0, 0);
                    acc1[i][n] = __builtin_amdgcn_mfma_f32_16x16x32_bf16(a2[i], p1, acc1[i][n], 0, 0, 0);
                }
            }
            {   // mat 1 -> acc2
                bf16x8 p1 = *(const bf16x8*)&sm.w1[(4 + jloc) * 512 + l8];
                bf16x8 p2 = *(const bf16x8*)&sm.w2[(4 + jloc) * 512 + l8];
                #pragma unroll
                for (int i = 0; i < 4; ++i) {
                    acc2[i][n] = __builtin_amdgcn_mfma_f32_16x16x32_bf16(a1[i], p1, acc2[i][n], 0, 0, 0);
                    acc2[i][n] = __builtin_amdgcn_mfma_f32_16x16x32_bf16(a1[i], p2, acc2[i][n], 0, 0, 0);
                    acc2[i][n] = __builtin_amdgcn_mfma_f32_16x16x32_bf16(a2[i], p1, acc2[i][n], 0, 0, 0);
                }
            }
            {   // E -> accE
                bf16x8 pe = *(const bf16x8*)&sm.we[jloc * 512 + l8];
                #pragma unroll
                for (int i = 0; i < 4; ++i)
                    accE[i][n] = __builtin_amdgcn_mfma_f32_16x16x32_bf16(a1[i], pe, accE[i][n], 0, 0, 0);
            }
        }
    }

    // ---- epilogue: in-register gate via lr-group butterflies ----
    float bc1[2], bc2[2], be[2];
    #pragma unroll
    for (int n = 0; n < 2; ++n) {
        int col = jBase + wn * 32 + n * 16 + lr;
        bc1[n] = Bc[col];
        bc2[n] = Bc[NJ + col];
        be[n]  = Bce[col];
    }
    const int gbase = l & 48;       // lr-group base lane
    #pragma unroll
    for (int i = 0; i < 4; ++i)
        #pragma unroll
        for (int n = 0; n < 2; ++n) {
            int colL = wn * 32 + n * 16 + lr;
            int dloc = wn * 2 + n;
            #pragma unroll
            for (int r = 0; r < 4; ++r) {
                int rowL = wm * 64 + i * 16 + lq * 4 + r;
                float m1 = acc1[i][n][r] + bc1[n];
                float m2 = acc2[i][n][r] + bc2[n];
                float nz = noise[(size_t)(sBase + rowL) * NJ + jBase + colL];
                float m  = fmaf(m2, nz, m1);
                float ev = accE[i][n][r] + be[n];
                float v1 = m; int i1 = lr;
                #pragma unroll
                for (int mk = 1; mk <= 8; mk <<= 1) {
                    float ov = __shfl_xor(v1, mk);
                    int oi = __shfl_xor(i1, mk);
                    if (ov > v1 || (ov == v1 && oi < i1)) { v1 = ov; i1 = oi; }
                }
                float v2 = (lr == i1) ? -INFINITY : m;
                int i2 = (lr == i1) ? 64 : lr;
                #pragma unroll
                for (int mk = 1; mk <= 8; mk <<= 1) {
                    float ov = __shfl_xor(v2, mk);
                    int oi = __shfl_xor(i2, mk);
                    if (ov > v2 || (ov == v2 && oi < i2)) { v2 = ov; i2 = oi; }
                }
                float v3 = (lr == i1 || lr == i2) ? -INFINITY : m;
                #pragma unroll
                for (int mk = 1; mk <= 8; mk <<= 1)
                    v3 = fmaxf(v3, __shfl_xor(v3, mk));
                float ev1 = __shfl(ev, gbase + i1);
                float ev2 = __shfl(ev, gbase + (i2 & 15));
                if (lr == 0) {
                    int gidx = (sBase + rowL) * DIMD + dBase + dloc;
                    bool flg = (v2 - v3 < GAP_T) || (fabsf(v1) < GAP_T) || (fabsf(v2) < GAP_T);
                    if (flg) {
                        int pos = atomicAdd(cnt, 1);
                        wl[pos] = gidx;
                    }
                    double x1 = (double)v1, x2 = (double)v2;
                    double vmax = fmax(x1, x2);
                    double g1 = exp(x1 - vmax), g2 = exp(x2 - vmax);
                    double num = g1 * (double)ev1 + g2 * (double)ev2;
                    out[gidx] = (float)(num / (g1 + g2) * 0.0625);
                }
            }
        }
}

// ---- repair: one wave per flagged site; lane = (expert, mat) exact chain ----
__global__ __launch_bounds__(256) void k_repair(
    const float* __restrict__ u, const float* __restrict__ noise,
    const float* __restrict__ Wnn, const float* __restrict__ Wno, const float* __restrict__ WE,
    const float* __restrict__ bnn, const float* __restrict__ bno, const float* __restrict__ bE,
    const float* __restrict__ R32,
    const int* __restrict__ cnt, const int* __restrict__ wl, float* __restrict__ out)
{
    const int l = threadIdx.x & 63;
    const int e = l & 15, mt = l >> 4;          // mt in 0..3 (3 idle)
    const int wid = (blockIdx.x * 256 + threadIdx.x) >> 6;
    const int NW = (1024 * 256) >> 6;           // 4096 waves: ~1 site each
    const int n = *cnt;

    for (int i = wid; i < n; i += NW) {
        int si = wl[i];
        int s = si >> 9, d = si & 511;
        int j = d * 16 + e;
        const float* urow = u + (size_t)s * KU;
        float t = 0.f;
        if (mt < 3) {
            const float* Wrow = (mt == 0 ? Wnn : (mt == 1 ? Wno : WE)) + (size_t)j * KF;
            #pragma unroll
            for (int c = 0; c < 4; ++c) {
                float cc = 0.f;
                int k0 = c * KC;
                #pragma unroll 4
                for (int k = k0; k < k0 + KC; ++k) {
                    float a = (k < KU) ? urow[k] : R32[k - KU];
                    cc = fmaf(a, Wrow[k], cc);
                }
                t = __fadd_rn(t, cc);
            }
            t = __fadd_rn(t, (mt == 0 ? bnn : (mt == 1 ? bno : bE))[j]);
        }
        float h2 = __shfl(t, 16 + e);
        float ee = __shfl(t, 32 + e);
        float m = -INFINITY;
        if (mt == 0)
            m = __fadd_rn(t, __fmul_rn(h2, noise[(size_t)s * NJ + j]));
        float v1 = m; int i1 = e;
        #pragma unroll
        for (int mk = 1; mk <= 8; mk <<= 1) {
            float ov = __shfl_xor(v1, mk);
            int oi = __shfl_xor(i1, mk);
            if (ov > v1 || (ov == v1 && oi < i1)) { v1 = ov; i1 = oi; }
        }
        float v2 = (mt == 0 && e == i1) ? -INFINITY : m;
        int i2 = (mt == 0 && e == i1) ? 64 : e;
        #pragma unroll
        for (int mk = 1; mk <= 8; mk <<= 1) {
            float ov = __shfl_xor(v2, mk);
            int oi = __shfl_xor(i2, mk);
            if (ov > v2 || (ov == v2 && oi < i2)) { v2 = ov; i2 = oi; }
        }
        float se = ee;
        #pragma unroll
        for (int mk = 1; mk <= 8; mk <<= 1) se += __shfl_xor(se, mk);
        float ev1 = __shfl(ee, i1);
        float ev2 = __shfl(ee, i2 & 15);
        if (l == 0) {
            double x1 = (v1 == 0.0f) ? -100000.0 : (double)v1;
            double x2 = (v2 == 0.0f) ? -100000.0 : (double)v2;
            double vmax = fmax(fmax(x1, x2), -100000.0);
            double g1 = exp(x1 - vmax), g2 = exp(x2 - vmax), gz = exp(-100000.0 - vmax);
            double den = g1 + g2 + 14.0 * gz;
            double num = g1 * (double)ev1 + g2 * (double)ev2
                       + gz * ((double)se - (double)ev1 - (double)ev2);
            out[si] = (float)(num / den * 0.0625);
        }
    }
}

// ---- fallback: proven round-5 ws-free kernel (bit-identical arithmetic) ----
__global__ __launch_bounds__(256) void k_base(
    const float* __restrict__ u, const float* __restrict__ noise,
    const float* __restrict__ Wnn, const float* __restrict__ Wno, const float* __restrict__ WE,
    const float* __restrict__ bnn, const float* __restrict__ bno, const float* __restrict__ bE,
    const float* __restrict__ h, const float* __restrict__ us, const float* __restrict__ ue,
    const float* __restrict__ Wr, const float* __restrict__ br,
    float* __restrict__ out)
{
    __shared__ __align__(16) float As[BM][PA];
    __shared__ __align__(16) float Ws[3][BK][PW];
    __shared__ float Rsh[512];

    const int tid = threadIdx.x;
    const int sr = tid >> 2, dl = tid & 3;
    const int jBase = blockIdx.x * 64;
    const int sBase = blockIdx.y * BM;
    const int myCol = dl * 16;

    for (int o = tid; o < 512; o += 256) Rsh[o] = chainR(h, us, ue, Wr, br, o);

    float t1[16] = {}, c1[16] = {}, t2[16] = {}, c2[16] = {}, tE[16] = {}, cE[16] = {};

    for (int kt = 0; kt < KF; kt += BK) {
        __syncthreads();
        if (kt < KU) {
            for (int idx = tid; idx < BM * BK; idx += 256) {
                int r = idx >> 5, c = idx & 31;
                As[r][c] = u[(size_t)(sBase + r) * KU + kt + c];
            }
        }
        for (int idx = tid; idx < 64 * BK; idx += 256) {
            int col = idx >> 5, kk = idx & 31;
            size_t off = (size_t)(jBase + col) * KF + kt + kk;
            Ws[0][kk][col] = Wnn[off];
            Ws[1][kk][col] = Wno[off];
            Ws[2][kk][col] = WE[off];
        }
        __syncthreads();
        const bool uReg = (kt < KU);
        for (int kk = 0; kk < BK; ++kk) {
            float a = uReg ? As[sr][kk] : Rsh[kt + kk - KU];
            #pragma unroll
            for (int q = 0; q < 4; ++q) {
                float4 w0 = *(const float4*)&Ws[0][kk][myCol + 4 * q];
                float4 w1 = *(const float4*)&Ws[1][kk][myCol + 4 * q];
                float4 w2 = *(const float4*)&Ws[2][kk][myCol + 4 * q];
                c1[4*q+0] = fmaf(a, w0.x, c1[4*q+0]);
                c1[4*q+1] = fmaf(a, w0.y, c1[4*q+1]);
                c1[4*q+2] = fmaf(a, w0.z, c1[4*q+2]);
                c1[4*q+3] = fmaf(a, w0.w, c1[4*q+3]);
                c2[4*q+0] = fmaf(a, w1.x, c2[4*q+0]);
                c2[4*q+1] = fmaf(a, w1.y, c2[4*q+1]);
                c2[4*q+2] = fmaf(a, w1.z, c2[4*q+2]);
                c2[4*q+3] = fmaf(a, w1.w, c2[4*q+3]);
                cE[4*q+0] = fmaf(a, w2.x, cE[4*q+0]);
                cE[4*q+1] = fmaf(a, w2.y, cE[4*q+1]);
                cE[4*q+2] = fmaf(a, w2.z, cE[4*q+2]);
                cE[4*q+3] = fmaf(a, w2.w, cE[4*q+3]);
            }
        }
        if (((kt + BK) % KC) == 0 || (kt + BK) == KF) {
            #pragma unroll
            for (int e = 0; e < 16; ++e) {
                t1[e] = __fadd_rn(t1[e], c1[e]); c1[e] = 0.f;
                t2[e] = __fadd_rn(t2[e], c2[e]); c2[e] = 0.f;
                tE[e] = __fadd_rn(tE[e], cE[e]); cE[e] = 0.f;
            }
        }
    }

    const int s = sBase + sr;
    const int jb = jBase + myCol;
    float m32[16]; double evv[16];
    #pragma unroll
    for (int e = 0; e < 16; ++e) {
        float h1 = __fadd_rn(t1[e], bnn[jb + e]);
        float h2 = __fadd_rn(t2[e], bno[jb + e]);
        float nz = noise[(size_t)s * NJ + jb + e];
        m32[e] = __fadd_rn(h1, __fmul_rn(h2, nz));
        evv[e] = (double)__fadd_rn(tE[e], bE[jb + e]);
    }
    int i1 = 0; float v1 = m32[0];
    #pragma unroll
    for (int e = 1; e < 16; ++e) if (m32[e] > v1) { v1 = m32[e]; i1 = e; }
    int i2 = -1; float v2 = -INFINITY;
    #pragma unroll
    for (int e = 0; e < 16; ++e) if (e != i1 && m32[e] > v2) { v2 = m32[e]; i2 = e; }
    double e1 = 0.0, e2 = 0.0, sumE = 0.0;
    #pragma unroll
    for (int e = 0; e < 16; ++e) {
        e1 = (e == i1) ? evv[e] : e1;
        e2 = (e == i2) ? evv[e] : e2;
        sumE += evv[e];
    }
    double x1 = (v1 == 0.0f) ? -100000.0 : (double)v1;
    double x2 = (v2 == 0.0f) ? -100000.0 : (double)v2;
    double vmax = fmax(fmax(x1, x2), -100000.0);
    double g1 = exp(x1 - vmax), g2 = exp(x2 - vmax), gz = exp(-100000.0 - vmax);
    double den = g1 + g2 + 14.0 * gz;
    double num = g1 * e1 + g2 * e2 + gz * (sumE - e1 - e2);
    out[(size_t)s * DIMD + (jBase >> 4) + dl] = (float)(num / den * 0.0625);
}

extern "C" void kernel_launch(void* const* d_in, const int* in_sizes, int n_in,
                              void* d_out, int out_size, void* d_ws, size_t ws_size,
                              hipStream_t stream) {
    (void)in_sizes; (void)n_in; (void)out_size;
    const float* h     = (const float*)d_in[0];
    const float* us    = (const float*)d_in[1];
    const float* ue    = (const float*)d_in[2];
    const float* u     = (const float*)d_in[3];
    const float* noise = (const float*)d_in[4];
    const float* Wnn   = (const float*)d_in[5];
    const float* bnn   = (const float*)d_in[6];
    const float* Wno   = (const float*)d_in[7];
    const float* bno   = (const float*)d_in[8];
    const float* WE    = (const float*)d_in[9];
    const float* bE    = (const float*)d_in[10];
    const float* Wr    = (const float*)d_in[11];
    const float* br    = (const float*)d_in[12];
    float* out = (float*)d_out;

    if (ws_size >= WS_NEEDED) {
        char* ws = (char*)d_ws;
        float* Rws  = (float*)(ws + WS_R);
        float* Bc   = (float*)(ws + WS_BC);
        float* Bce  = (float*)(ws + WS_BCE);
        int*   cnt  = (int*)(ws + WS_CNT);
        int*   wl   = (int*)(ws + WS_WL);
        ushort* uhi = (ushort*)(ws + WS_UHI);
        ushort* ulo = (ushort*)(ws + WS_ULO);
        ushort* whi = (ushort*)(ws + WS_WHI);
        ushort* wlo = (ushort*)(ws + WS_WLO);
        ushort* weh = (ushort*)(ws + WS_WEH);

        hipLaunchKernelGGL(k_R32, dim3(8), dim3(256), 0, stream, h, us, ue, Wr, br, Rws, cnt);
        hipLaunchKernelGGL(k_prep_u, dim3(SEQL / 16), dim3(256), 0, stream, u, uhi, ulo);
        hipLaunchKernelGGL(k_prep_w, dim3(2 * NJ / 16), dim3(256), 0, stream, Wnn, Wno, whi, wlo);
        hipLaunchKernelGGL(k_prep_we, dim3(NJ / 16), dim3(256), 0, stream, WE, weh);
        hipLaunchKernelGGL(k_bias, dim3(6144), dim3(256), 0, stream,
                           Rws, Wnn, Wno, WE, bnn, bno, bE, Bc, Bce);
        hipLaunchKernelGGL(k_m, dim3(NJ / 64, SEQL / 128), dim3(256), 0, stream,
                           uhi, ulo, whi, wlo, weh, noise, Bc, Bce, cnt, wl, out);
        hipLaunchKernelGGL(k_repair, dim3(1024), dim3(256), 0, stream,
                           u, noise, Wnn, Wno, WE, bnn, bno, bE, Rws, cnt, wl, out);
    } else {
        hipLaunchKernelGGL(k_base, dim3(NJ / 64, SEQL / BM), dim3(256), 0, stream,
                           u, noise, Wnn, Wno, WE, bnn, bno, bE,
                           h, us, ue, Wr, br, out);
    }
}

// Round 14
// 808.304 us; speedup vs baseline: 2.7460x; 2.0159x over previous
//
#include <hip/hip_runtime.h>
#include <hip/hip_bf16.h>
#include <math.h>

#define DIMD 512
#define SEQL 4096
#define KU 1024
#define KF 1536
#define NJ 8192
#define KC 384          // OpenBLAS sgemm K-blocking (matched in round 5)
#define NTK 32          // KU/32 k-tiles

#define BM 64
#define BK 32
#define PA 33
#define PW 68

#define GAP_T 1e-4f     // r14: tightened from 1e-3 (error model: |m_fast-m_ref| tail ~1e-5)

// ---- ws layout (bytes) ----
#define WS_R    0u          // 512 f32
#define WS_BC   4096u       // 2*8192 f32 (m-path combined bias, f64-folded)
#define WS_BCE  69632u      // 8192 f32 (e-path combined bias, f64-folded)
#define WS_CNT  102400u     // int counter
#define WS_WL   102656u     // worklist (2.1M ints max)
#define WS_UHI  8491264u    // 4096*1024 bf16, fragment order
#define WS_ULO  16879872u   // 4096*1024 bf16, fragment order
#define WS_WHI  25268480u   // 2*8192*1024 bf16 (Wnn,Wno hi), fragment order
#define WS_WLO  58822912u   // 2*8192*1024 bf16 (lo), fragment order
#define WS_WEH  92377344u   // 8192*1024 bf16 (W_E hi), fragment order
#define WS_NEEDED 109154560u

typedef __attribute__((ext_vector_type(8))) short bf16x8;
typedef __attribute__((ext_vector_type(4))) float f32x4;

__device__ __forceinline__ ushort f2bf(float f) {
    __hip_bfloat16 h = __float2bfloat16(f);
    return *reinterpret_cast<ushort*>(&h);
}
__device__ __forceinline__ float bf2f(ushort v) {
    unsigned int b = ((unsigned int)v) << 16;
    return __uint_as_float(b);
}

// ---- f32 R with the exact chunked fma chain (k-ascending, KC blocks) ----
__device__ __forceinline__ float chainR(
    const float* __restrict__ h, const float* __restrict__ us, const float* __restrict__ ue,
    const float* __restrict__ Wr, const float* __restrict__ br, int o)
{
    float accT = 0.f;
    for (int k0 = 0; k0 < 2560; k0 += KC) {
        int ke = (k0 + KC < 2560) ? k0 + KC : 2560;
        float accC = 0.f;
        for (int k = k0; k < ke; ++k) {
            float xv = (k < 1536) ? h[k] : (k < 2048) ? us[k - 1536] : ue[k - 2048];
            accC = fmaf(xv, Wr[(size_t)o * 2560 + k], accC);
        }
        accT = __fadd_rn(accT, accC);
    }
    return __fadd_rn(accT, br[o]);
}

// ---- R: 8 blocks x 64 outputs; Wr staged to LDS coalesced; exact chain order ----
#define KCP 385
__global__ __launch_bounds__(256) void k_R32(
    const float* __restrict__ h, const float* __restrict__ us, const float* __restrict__ ue,
    const float* __restrict__ Wr, const float* __restrict__ br,
    float* __restrict__ Rout, int* __restrict__ cnt)
{
    __shared__ float xs[2560];
    __shared__ float Wsh[64 * KCP];
    if (blockIdx.x == 0 && threadIdx.x == 0) *cnt = 0;
    const int tid = threadIdx.x;
    const int o0 = blockIdx.x * 64;
    for (int k = tid; k < 2560; k += 256)
        xs[k] = (k < 1536) ? h[k] : (k < 2048) ? us[k - 1536] : ue[k - 2048];
    float accT = 0.f;
    for (int c = 0; c < 7; ++c) {
        int k0 = c * KC;
        int len = (k0 + KC <= 2560) ? KC : (2560 - k0);
        __syncthreads();
        for (int idx = tid * 4; idx < 64 * len; idx += 1024) {
            int r = idx / len, kk = idx - r * len;
            *(float4*)&Wsh[r * KCP + kk] = *(const float4*)&Wr[(size_t)(o0 + r) * 2560 + k0 + kk];
        }
        __syncthreads();
        if (tid < 64) {
            float accC = 0.f;
            for (int k = 0; k < len; ++k)
                accC = fmaf(xs[k0 + k], Wsh[tid * KCP + k], accC);
            accT = __fadd_rn(accT, accC);
        }
    }
    if (tid < 64) Rout[o0 + tid] = __fadd_rn(accT, br[o0 + tid]);
}

// ---- prep u: block per s16-tile; coalesced read -> LDS -> coalesced frag write ----
#define LPAD 1032
__global__ __launch_bounds__(256) void k_prep_u(
    const float* __restrict__ u, ushort* __restrict__ uhi, ushort* __restrict__ ulo)
{
    __shared__ ushort hs[16 * LPAD], ls[16 * LPAD];
    const int tid = threadIdx.x;
    const int t16 = blockIdx.x;
    #pragma unroll
    for (int it = 0; it < 16; ++it) {
        int k = tid * 4;
        float4 v = *(const float4*)&u[((size_t)t16 * 16 + it) * KU + k];
        ushort4 a, b;
        a.x = f2bf(v.x); b.x = f2bf(v.x - bf2f(a.x));
        a.y = f2bf(v.y); b.y = f2bf(v.y - bf2f(a.y));
        a.z = f2bf(v.z); b.z = f2bf(v.z - bf2f(a.z));
        a.w = f2bf(v.w); b.w = f2bf(v.w - bf2f(a.w));
        *(ushort4*)&hs[it * LPAD + k] = a;
        *(ushort4*)&ls[it * LPAD + k] = b;
    }
    __syncthreads();
    #pragma unroll
    for (int ct = 0; ct < 8; ++ct) {
        int c = ct * 256 + tid;
        int k32 = c >> 6, l = c & 63;
        int src = (l & 15) * LPAD + k32 * 32 + (l >> 4) * 8;
        size_t dst = (((size_t)t16 * NTK + k32) * 64 + l) * 8;
        *(uint4*)&uhi[dst] = *(const uint4*)&hs[src];
        *(uint4*)&ulo[dst] = *(const uint4*)&ls[src];
    }
}

// ---- prep Wnn/Wno: block per (mat, j16); hi+lo ----
__global__ __launch_bounds__(256) void k_prep_w(
    const float* __restrict__ Wnn, const float* __restrict__ Wno,
    ushort* __restrict__ whi, ushort* __restrict__ wlo)
{
    __shared__ ushort hs[16 * LPAD], ls[16 * LPAD];
    const int tid = threadIdx.x;
    const int mat = blockIdx.x >> 9, j16 = blockIdx.x & 511;
    const float* W = mat ? Wno : Wnn;
    #pragma unroll
    for (int it = 0; it < 16; ++it) {
        int k = tid * 4;
        float4 v = *(const float4*)&W[((size_t)j16 * 16 + it) * KF + k];
        ushort4 a, b;
        a.x = f2bf(v.x); b.x = f2bf(v.x - bf2f(a.x));
        a.y = f2bf(v.y); b.y = f2bf(v.y - bf2f(a.y));
        a.z = f2bf(v.z); b.z = f2bf(v.z - bf2f(a.z));
        a.w = f2bf(v.w); b.w = f2bf(v.w - bf2f(a.w));
        *(ushort4*)&hs[it * LPAD + k] = a;
        *(ushort4*)&ls[it * LPAD + k] = b;
    }
    __syncthreads();
    #pragma unroll
    for (int ct = 0; ct < 8; ++ct) {
        int c = ct * 256 + tid;
        int k32 = c >> 6, l = c & 63;
        int src = (l & 15) * LPAD + k32 * 32 + (l >> 4) * 8;
        size_t dst = ((((size_t)mat * 512 + j16) * NTK + k32) * 64 + l) * 8;
        *(uint4*)&whi[dst] = *(const uint4*)&hs[src];
        *(uint4*)&wlo[dst] = *(const uint4*)&ls[src];
    }
}

// ---- prep W_E: block per j16; hi only ----
__global__ __launch_bounds__(256) void k_prep_we(
    const float* __restrict__ WE, ushort* __restrict__ weh)
{
    __shared__ ushort hs[16 * LPAD];
    const int tid = threadIdx.x;
    const int j16 = blockIdx.x;
    #pragma unroll
    for (int it = 0; it < 16; ++it) {
        int k = tid * 4;
        float4 v = *(const float4*)&WE[((size_t)j16 * 16 + it) * KF + k];
        ushort4 a;
        a.x = f2bf(v.x); a.y = f2bf(v.y); a.z = f2bf(v.z); a.w = f2bf(v.w);
        *(ushort4*)&hs[it * LPAD + k] = a;
    }
    __syncthreads();
    #pragma unroll
    for (int ct = 0; ct < 8; ++ct) {
        int c = ct * 256 + tid;
        int k32 = c >> 6, l = c & 63;
        int src = (l & 15) * LPAD + k32 * 32 + (l >> 4) * 8;
        size_t dst = (((size_t)j16 * NTK + k32) * 64 + l) * 8;
        *(uint4*)&weh[dst] = *(const uint4*)&hs[src];
    }
}

// ---- merged bias: mat 0,1 -> Bc; mat 2 -> Bce (f64 fold, wave per output) ----
__global__ __launch_bounds__(256) void k_bias(
    const float* __restrict__ R32,
    const float* __restrict__ Wnn, const float* __restrict__ Wno, const float* __restrict__ WE,
    const float* __restrict__ bnn, const float* __restrict__ bno, const float* __restrict__ bE,
    float* __restrict__ Bc, float* __restrict__ Bce)
{
    int wid = blockIdx.x * 4 + (threadIdx.x >> 6);   // 0..24575
    int l = threadIdx.x & 63;
    int mat = wid >> 13, j = wid & 8191;
    const float* W = (mat == 0) ? Wnn : (mat == 1) ? Wno : WE;
    const float* b = (mat == 0) ? bnn : (mat == 1) ? bno : bE;
    double acc = 0.0;
    for (int k = 1024 + l; k < 1536; k += 64)
        acc += (double)R32[k - KU] * (double)W[(size_t)j * KF + k];
    for (int off = 32; off > 0; off >>= 1) acc += __shfl_down(acc, off);
    if (l == 0) {
        float r = (float)(acc + (double)b[j]);
        if (mat < 2) Bc[wid] = r; else Bce[j] = r;
    }
}

// ---- fused m+e kernel: linear fragment LDS, shuffle gate (round-11 proven) ----
struct MSt {
    ushort u1[4096], u2[4096];    // 8 s16-tiles x 64 lanes x 8
    ushort w1[4096], w2[4096];    // (2 mats x 4 j16-tiles) x 64 x 8
    ushort we[2048];              // 4 j16-tiles x 64 x 8
};                                // 36864 B

__global__ __launch_bounds__(256, 3) void k_m(
    const ushort* __restrict__ uhi, const ushort* __restrict__ ulo,
    const ushort* __restrict__ whi, const ushort* __restrict__ wlo,
    const ushort* __restrict__ weh,
    const float* __restrict__ noise,
    const float* __restrict__ Bc, const float* __restrict__ Bce,
    int* __restrict__ cnt, int* __restrict__ wl, float* __restrict__ out)
{
    __shared__ MSt sm;
    const int tid = threadIdx.x;
    const int w = tid >> 6, l = tid & 63;
    const int wm = w >> 1, wn = w & 1;
    const int lr = l & 15, lq = l >> 4;
    const int l8 = l * 8;
    const int sBase = blockIdx.y * 128;
    const int sB16 = blockIdx.y * 8;
    const int jBase = blockIdx.x * 64;
    const int jB16 = blockIdx.x * 4;
    const int dBase = jBase >> 4;

    f32x4 acc1[4][2] = {}, acc2[4][2] = {}, accE[4][2] = {};

    for (int kt = 0; kt < NTK; ++kt) {
        __syncthreads();
        #pragma unroll
        for (int it = 0; it < 4; ++it) {            // u: 1024 x 16B
            int c = tid + it * 256;
            int buf = c >> 9, rem = c & 511;
            size_t g = (((size_t)(sB16 + (rem >> 6)) * NTK + kt) * 64 + (rem & 63)) * 8;
            const ushort* src = buf ? ulo : uhi;
            ushort* dst = (buf ? sm.u2 : sm.u1) + rem * 8;
            *(uint4*)dst = *(const uint4*)&src[g];
        }
        #pragma unroll
        for (int it = 0; it < 4; ++it) {            // w: 1024 x 16B
            int c = tid + it * 256;
            int buf = c >> 9, rem = c & 511;
            int mt = rem >> 8, jt = (rem >> 6) & 3;
            size_t g = ((((size_t)mt * 512 + jB16 + jt) * NTK + kt) * 64 + (rem & 63)) * 8;
            const ushort* src = buf ? wlo : whi;
            ushort* dst = (buf ? sm.w2 : sm.w1) + rem * 8;
            *(uint4*)dst = *(const uint4*)&src[g];
        }
        {                                           // we: 256 x 16B
            int jt = tid >> 6;
            size_t g = (((size_t)(jB16 + jt) * NTK + kt) * 64 + (tid & 63)) * 8;
            *(uint4*)&sm.we[tid * 8] = *(const uint4*)&weh[g];
        }
        __syncthreads();
        bf16x8 a1[4], a2[4];
        #pragma unroll
        for (int i = 0; i < 4; ++i) {
            int base = (wm * 4 + i) * 512 + l8;
            a1[i] = *(const bf16x8*)&sm.u1[base];
            a2[i] = *(const bf16x8*)&sm.u2[base];
        }
        #pragma unroll
        for (int n = 0; n < 2; ++n) {
            int jloc = wn * 2 + n;
            {   // mat 0 -> acc1
                bf16x8 p1 = *(const bf16x8*)&sm.w1[jloc * 512 + l8];
                bf16x8 p2 = *(const bf16x8*)&sm.w2[jloc * 512 + l8];
                #pragma unroll
                for (int i = 0; i < 4; ++i) {
                    acc1[i][n] = __builtin_amdgcn_mfma_f32_16x16x32_bf16(a1[i], p1, acc1[i][n], 0, 0, 0);
                    acc1[i][n] = __builtin_amdgcn_mfma_f32_16x16x32_bf16(a1[i], p2, acc1[i][n], 0, 0, 0);
                    acc1[i][n] = __builtin_amdgcn_mfma_f32_16x16x32_bf16(a2[i], p1, acc1[i][n], 0, 0, 0);
                }
            }
            {   // mat 1 -> acc2
                bf16x8 p1 = *(const bf16x8*)&sm.w1[(4 + jloc) * 512 + l8];
                bf16x8 p2 = *(const bf16x8*)&sm.w2[(4 + jloc) * 512 + l8];
                #pragma unroll
                for (int i = 0; i < 4; ++i) {
                    acc2[i][n] = __builtin_amdgcn_mfma_f32_16x16x32_bf16(a1[i], p1, acc2[i][n], 0, 0, 0);
                    acc2[i][n] = __builtin_amdgcn_mfma_f32_16x16x32_bf16(a1[i], p2, acc2[i][n], 0, 0, 0);
                    acc2[i][n] = __builtin_amdgcn_mfma_f32_16x16x32_bf16(a2[i], p1, acc2[i][n], 0, 0, 0);
                }
            }
            {   // E -> accE
                bf16x8 pe = *(const bf16x8*)&sm.we[jloc * 512 + l8];
                #pragma unroll
                for (int i = 0; i < 4; ++i)
                    accE[i][n] = __builtin_amdgcn_mfma_f32_16x16x32_bf16(a1[i], pe, accE[i][n], 0, 0, 0);
            }
        }
    }

    // ---- epilogue: in-register gate via lr-group butterflies ----
    float bc1[2], bc2[2], be[2];
    #pragma unroll
    for (int n = 0; n < 2; ++n) {
        int col = jBase + wn * 32 + n * 16 + lr;
        bc1[n] = Bc[col];
        bc2[n] = Bc[NJ + col];
        be[n]  = Bce[col];
    }
    const int gbase = l & 48;       // lr-group base lane
    #pragma unroll
    for (int i = 0; i < 4; ++i)
        #pragma unroll
        for (int n = 0; n < 2; ++n) {
            int colL = wn * 32 + n * 16 + lr;
            int dloc = wn * 2 + n;
            #pragma unroll
            for (int r = 0; r < 4; ++r) {
                int rowL = wm * 64 + i * 16 + lq * 4 + r;
                float m1 = acc1[i][n][r] + bc1[n];
                float m2 = acc2[i][n][r] + bc2[n];
                float nz = noise[(size_t)(sBase + rowL) * NJ + jBase + colL];
                float m  = fmaf(m2, nz, m1);
                float ev = accE[i][n][r] + be[n];
                float v1 = m; int i1 = lr;
                #pragma unroll
                for (int mk = 1; mk <= 8; mk <<= 1) {
                    float ov = __shfl_xor(v1, mk);
                    int oi = __shfl_xor(i1, mk);
                    if (ov > v1 || (ov == v1 && oi < i1)) { v1 = ov; i1 = oi; }
                }
                float v2 = (lr == i1) ? -INFINITY : m;
                int i2 = (lr == i1) ? 64 : lr;
                #pragma unroll
                for (int mk = 1; mk <= 8; mk <<= 1) {
                    float ov = __shfl_xor(v2, mk);
                    int oi = __shfl_xor(i2, mk);
                    if (ov > v2 || (ov == v2 && oi < i2)) { v2 = ov; i2 = oi; }
                }
                float v3 = (lr == i1 || lr == i2) ? -INFINITY : m;
                #pragma unroll
                for (int mk = 1; mk <= 8; mk <<= 1)
                    v3 = fmaxf(v3, __shfl_xor(v3, mk));
                float ev1 = __shfl(ev, gbase + i1);
                float ev2 = __shfl(ev, gbase + (i2 & 15));
                if (lr == 0) {
                    int gidx = (sBase + rowL) * DIMD + dBase + dloc;
                    bool flg = (v2 - v3 < GAP_T) || (fabsf(v1) < GAP_T) || (fabsf(v2) < GAP_T);
                    if (flg) {
                        int pos = atomicAdd(cnt, 1);
                        wl[pos] = gidx;
                    }
                    double x1 = (double)v1, x2 = (double)v2;
                    double vmax = fmax(x1, x2);
                    double g1 = exp(x1 - vmax), g2 = exp(x2 - vmax);
                    double num = g1 * (double)ev1 + g2 * (double)ev2;
                    out[gidx] = (float)(num / (g1 + g2) * 0.0625);
                }
            }
        }
}

// ---- repair: one wave per flagged site; lane = (expert, mat) exact chain ----
__global__ __launch_bounds__(256) void k_repair(
    const float* __restrict__ u, const float* __restrict__ noise,
    const float* __restrict__ Wnn, const float* __restrict__ Wno, const float* __restrict__ WE,
    const float* __restrict__ bnn, const float* __restrict__ bno, const float* __restrict__ bE,
    const float* __restrict__ R32,
    const int* __restrict__ cnt, const int* __restrict__ wl, float* __restrict__ out)
{
    const int l = threadIdx.x & 63;
    const int e = l & 15, mt = l >> 4;          // mt in 0..3 (3 idle)
    const int wid = (blockIdx.x * 256 + threadIdx.x) >> 6;
    const int NW = (1024 * 256) >> 6;           // 4096 waves
    const int n = *cnt;

    for (int i = wid; i < n; i += NW) {
        int si = wl[i];
        int s = si >> 9, d = si & 511;
        int j = d * 16 + e;
        const float* urow = u + (size_t)s * KU;
        float t = 0.f;
        if (mt < 3) {
            const float* Wrow = (mt == 0 ? Wnn : (mt == 1 ? Wno : WE)) + (size_t)j * KF;
            #pragma unroll
            for (int c = 0; c < 4; ++c) {
                float cc = 0.f;
                int k0 = c * KC;
                for (int k = k0; k < k0 + KC; ++k) {
                    float a = (k < KU) ? urow[k] : R32[k - KU];
                    cc = fmaf(a, Wrow[k], cc);
                }
                t = __fadd_rn(t, cc);
            }
            t = __fadd_rn(t, (mt == 0 ? bnn : (mt == 1 ? bno : bE))[j]);
        }
        float h2 = __shfl(t, 16 + e);
        float ee = __shfl(t, 32 + e);
        float m = -INFINITY;
        if (mt == 0)
            m = __fadd_rn(t, __fmul_rn(h2, noise[(size_t)s * NJ + j]));
        float v1 = m; int i1 = e;
        #pragma unroll
        for (int mk = 1; mk <= 8; mk <<= 1) {
            float ov = __shfl_xor(v1, mk);
            int oi = __shfl_xor(i1, mk);
            if (ov > v1 || (ov == v1 && oi < i1)) { v1 = ov; i1 = oi; }
        }
        float v2 = (mt == 0 && e == i1) ? -INFINITY : m;
        int i2 = (mt == 0 && e == i1) ? 64 : e;
        #pragma unroll
        for (int mk = 1; mk <= 8; mk <<= 1) {
            float ov = __shfl_xor(v2, mk);
            int oi = __shfl_xor(i2, mk);
            if (ov > v2 || (ov == v2 && oi < i2)) { v2 = ov; i2 = oi; }
        }
        float se = ee;
        #pragma unroll
        for (int mk = 1; mk <= 8; mk <<= 1) se += __shfl_xor(se, mk);
        float ev1 = __shfl(ee, i1);
        float ev2 = __shfl(ee, i2 & 15);
        if (l == 0) {
            double x1 = (v1 == 0.0f) ? -100000.0 : (double)v1;
            double x2 = (v2 == 0.0f) ? -100000.0 : (double)v2;
            double vmax = fmax(fmax(x1, x2), -100000.0);
            double g1 = exp(x1 - vmax), g2 = exp(x2 - vmax), gz = exp(-100000.0 - vmax);
            double den = g1 + g2 + 14.0 * gz;
            double num = g1 * (double)ev1 + g2 * (double)ev2
                       + gz * ((double)se - (double)ev1 - (double)ev2);
            out[si] = (float)(num / den * 0.0625);
        }
    }
}

// ---- fallback: proven round-5 ws-free kernel (bit-identical arithmetic) ----
__global__ __launch_bounds__(256) void k_base(
    const float* __restrict__ u, const float* __restrict__ noise,
    const float* __restrict__ Wnn, const float* __restrict__ Wno, const float* __restrict__ WE,
    const float* __restrict__ bnn, const float* __restrict__ bno, const float* __restrict__ bE,
    const float* __restrict__ h, const float* __restrict__ us, const float* __restrict__ ue,
    const float* __restrict__ Wr, const float* __restrict__ br,
    float* __restrict__ out)
{
    __shared__ __align__(16) float As[BM][PA];
    __shared__ __align__(16) float Ws[3][BK][PW];
    __shared__ float Rsh[512];

    const int tid = threadIdx.x;
    const int sr = tid >> 2, dl = tid & 3;
    const int jBase = blockIdx.x * 64;
    const int sBase = blockIdx.y * BM;
    const int myCol = dl * 16;

    for (int o = tid; o < 512; o += 256) Rsh[o] = chainR(h, us, ue, Wr, br, o);

    float t1[16] = {}, c1[16] = {}, t2[16] = {}, c2[16] = {}, tE[16] = {}, cE[16] = {};

    for (int kt = 0; kt < KF; kt += BK) {
        __syncthreads();
        if (kt < KU) {
            for (int idx = tid; idx < BM * BK; idx += 256) {
                int r = idx >> 5, c = idx & 31;
                As[r][c] = u[(size_t)(sBase + r) * KU + kt + c];
            }
        }
        for (int idx = tid; idx < 64 * BK; idx += 256) {
            int col = idx >> 5, kk = idx & 31;
            size_t off = (size_t)(jBase + col) * KF + kt + kk;
            Ws[0][kk][col] = Wnn[off];
            Ws[1][kk][col] = Wno[off];
            Ws[2][kk][col] = WE[off];
        }
        __syncthreads();
        const bool uReg = (kt < KU);
        for (int kk = 0; kk < BK; ++kk) {
            float a = uReg ? As[sr][kk] : Rsh[kt + kk - KU];
            #pragma unroll
            for (int q = 0; q < 4; ++q) {
                float4 w0 = *(const float4*)&Ws[0][kk][myCol + 4 * q];
                float4 w1 = *(const float4*)&Ws[1][kk][myCol + 4 * q];
                float4 w2 = *(const float4*)&Ws[2][kk][myCol + 4 * q];
                c1[4*q+0] = fmaf(a, w0.x, c1[4*q+0]);
                c1[4*q+1] = fmaf(a, w0.y, c1[4*q+1]);
                c1[4*q+2] = fmaf(a, w0.z, c1[4*q+2]);
                c1[4*q+3] = fmaf(a, w0.w, c1[4*q+3]);
                c2[4*q+0] = fmaf(a, w1.x, c2[4*q+0]);
                c2[4*q+1] = fmaf(a, w1.y, c2[4*q+1]);
                c2[4*q+2] = fmaf(a, w1.z, c2[4*q+2]);
                c2[4*q+3] = fmaf(a, w1.w, c2[4*q+3]);
                cE[4*q+0] = fmaf(a, w2.x, cE[4*q+0]);
                cE[4*q+1] = fmaf(a, w2.y, cE[4*q+1]);
                cE[4*q+2] = fmaf(a, w2.z, cE[4*q+2]);
                cE[4*q+3] = fmaf(a, w2.w, cE[4*q+3]);
            }
        }
        if (((kt + BK) % KC) == 0 || (kt + BK) == KF) {
            #pragma unroll
            for (int e = 0; e < 16; ++e) {
                t1[e] = __fadd_rn(t1[e], c1[e]); c1[e] = 0.f;
                t2[e] = __fadd_rn(t2[e], c2[e]); c2[e] = 0.f;
                tE[e] = __fadd_rn(tE[e], cE[e]); cE[e] = 0.f;
            }
        }
    }

    const int s = sBase + sr;
    const int jb = jBase + myCol;
    float m32[16]; double evv[16];
    #pragma unroll
    for (int e = 0; e < 16; ++e) {
        float h1 = __fadd_rn(t1[e], bnn[jb + e]);
        float h2 = __fadd_rn(t2[e], bno[jb + e]);
        float nz = noise[(size_t)s * NJ + jb + e];
        m32[e] = __fadd_rn(h1, __fmul_rn(h2, nz));
        evv[e] = (double)__fadd_rn(tE[e], bE[jb + e]);
    }
    int i1 = 0; float v1 = m32[0];
    #pragma unroll
    for (int e = 1; e < 16; ++e) if (m32[e] > v1) { v1 = m32[e]; i1 = e; }
    int i2 = -1; float v2 = -INFINITY;
    #pragma unroll
    for (int e = 0; e < 16; ++e) if (e != i1 && m32[e] > v2) { v2 = m32[e]; i2 = e; }
    double e1 = 0.0, e2 = 0.0, sumE = 0.0;
    #pragma unroll
    for (int e = 0; e < 16; ++e) {
        e1 = (e == i1) ? evv[e] : e1;
        e2 = (e == i2) ? evv[e] : e2;
        sumE += evv[e];
    }
    double x1 = (v1 == 0.0f) ? -100000.0 : (double)v1;
    double x2 = (v2 == 0.0f) ? -100000.0 : (double)v2;
    double vmax = fmax(fmax(x1, x2), -100000.0);
    double g1 = exp(x1 - vmax), g2 = exp(x2 - vmax), gz = exp(-100000.0 - vmax);
    double den = g1 + g2 + 14.0 * gz;
    double num = g1 * e1 + g2 * e2 + gz * (sumE - e1 - e2);
    out[(size_t)s * DIMD + (jBase >> 4) + dl] = (float)(num / den * 0.0625);
}

extern "C" void kernel_launch(void* const* d_in, const int* in_sizes, int n_in,
                              void* d_out, int out_size, void* d_ws, size_t ws_size,
                              hipStream_t stream) {
    (void)in_sizes; (void)n_in; (void)out_size;
    const float* h     = (const float*)d_in[0];
    const float* us    = (const float*)d_in[1];
    const float* ue    = (const float*)d_in[2];
    const float* u     = (const float*)d_in[3];
    const float* noise = (const float*)d_in[4];
    const float* Wnn   = (const float*)d_in[5];
    const float* bnn   = (const float*)d_in[6];
    const float* Wno   = (const float*)d_in[7];
    const float* bno   = (const float*)d_in[8];
    const float* WE    = (const float*)d_in[9];
    const float* bE    = (const float*)d_in[10];
    const float* Wr    = (const float*)d_in[11];
    const float* br    = (const float*)d_in[12];
    float* out = (float*)d_out;

    if (ws_size >= WS_NEEDED) {
        char* ws = (char*)d_ws;
        float* Rws  = (float*)(ws + WS_R);
        float* Bc   = (float*)(ws + WS_BC);
        float* Bce  = (float*)(ws + WS_BCE);
        int*   cnt  = (int*)(ws + WS_CNT);
        int*   wl   = (int*)(ws + WS_WL);
        ushort* uhi = (ushort*)(ws + WS_UHI);
        ushort* ulo = (ushort*)(ws + WS_ULO);
        ushort* whi = (ushort*)(ws + WS_WHI);
        ushort* wlo = (ushort*)(ws + WS_WLO);
        ushort* weh = (ushort*)(ws + WS_WEH);

        hipLaunchKernelGGL(k_R32, dim3(8), dim3(256), 0, stream, h, us, ue, Wr, br, Rws, cnt);
        hipLaunchKernelGGL(k_prep_u, dim3(SEQL / 16), dim3(256), 0, stream, u, uhi, ulo);
        hipLaunchKernelGGL(k_prep_w, dim3(2 * NJ / 16), dim3(256), 0, stream, Wnn, Wno, whi, wlo);
        hipLaunchKernelGGL(k_prep_we, dim3(NJ / 16), dim3(256), 0, stream, WE, weh);
        hipLaunchKernelGGL(k_bias, dim3(6144), dim3(256), 0, stream,
                           Rws, Wnn, Wno, WE, bnn, bno, bE, Bc, Bce);
        hipLaunchKernelGGL(k_m, dim3(NJ / 64, SEQL / 128), dim3(256), 0, stream,
                           uhi, ulo, whi, wlo, weh, noise, Bc, Bce, cnt, wl, out);
        hipLaunchKernelGGL(k_repair, dim3(1024), dim3(256), 0, stream,
                           u, noise, Wnn, Wno, WE, bnn, bno, bE, Rws, cnt, wl, out);
    } else {
        hipLaunchKernelGGL(k_base, dim3(NJ / 64, SEQL / BM), dim3(256), 0, stream,
                           u, noise, Wnn, Wno, WE, bnn, bno, bE,
                           h, us, ue, Wr, br, out);
    }
}